// Round 1
// baseline (444.941 us; speedup 1.0000x reference)
//
#include <hip/hip_runtime.h>

// FCNNRhoValuationFunction: rho = sqrt((z2c0-z1c0)^2 + (z1c2-z2c2)^2),
// dist_id = #{k in 1..9 : rho >= k*0.1f}, out[b] = dist_grade[b][dist_id].
//
// R1 (scalar strided) = 154 us, R2 (LDS float4 staging) = 153 us: identical.
// => TA serialization was NOT the binding constraint. Counters for R2:
//    VALUBusy 3.9%, HBM 22% of peak, Occupancy 42% -> latency-bound.
//    One-shot blocks (15625 launches) each pay: stage -> syncthreads
//    (vmcnt(0) drain for all waves) -> tiny compute -> exit. ~61 serial
//    block lifetimes per CU with only ~5-way overlap caps delivered BW
//    at ~3.4 TB/s effective (traffic floor is ~528 MB ~= 84 us @ 6.3 TB/s;
//    every 128B line of all 3 arrays is needed since the per-row byte gaps
//    are < 128B, so traffic cannot be reduced -- only latency hidden).
//
// R3: no LDS, no barriers. Grid-stride, 1024 blocks x 256 threads
// (T = 262144, B/T = 15.26). Each thread runs exactly three 5-row
// batches + <=1 scalar row: issue 20 independent dword loads, compute
// 5 ids, 5 independent dg gathers, 5 coalesced stores. ~80 KB/CU of
// loads continuously in flight, no barrier drains, 15x fewer launches.
// 32-bit indexing -> SADDR+voffset loads, low VGPR.
//
// IEEE ops (__f*_rn) keep us bit-identical to the numpy f32 reference:
// a 1-ulp diff can flip a threshold compare and change out by O(1).

#define ZD 11
#define GD 10

__device__ __forceinline__ int rho_bin(float a0, float a2, float c0, float c2)
{
    float dx  = __fadd_rn(c0, -a0);
    float dy  = __fadd_rn(a2, -c2);
    float s   = __fadd_rn(__fmul_rn(dx, dx), __fmul_rn(dy, dy));
    float rho = __fsqrt_rn(s);
    int id = 0;
    #pragma unroll
    for (int k = 1; k <= 9; ++k)
        id += (rho >= (float)k * 0.1f) ? 1 : 0;
    return id;
}

__global__ __launch_bounds__(256) void rho_valuation_kernel(
    const float* __restrict__ z1,
    const float* __restrict__ z2,
    const float* __restrict__ dg,
    float* __restrict__ out,
    int B)
{
    const int T = gridDim.x * blockDim.x;
    int i = blockIdx.x * blockDim.x + threadIdx.x;

    // ---- main: 5-row unrolled batches (all-int indexing, max 44M < 2^31) ----
    for (; i + 4 * T < B; i += 5 * T) {
        const int r0 = i, r1 = i + T, r2 = i + 2 * T, r3 = i + 3 * T, r4 = i + 4 * T;
        const int o0 = r0 * ZD, o1 = r1 * ZD, o2 = r2 * ZD, o3 = r3 * ZD, o4 = r4 * ZD;

        // issue all 20 independent loads first (compiler keeps them in flight)
        float a0_0 = z1[o0],     a2_0 = z1[o0 + 2];
        float a0_1 = z1[o1],     a2_1 = z1[o1 + 2];
        float a0_2 = z1[o2],     a2_2 = z1[o2 + 2];
        float a0_3 = z1[o3],     a2_3 = z1[o3 + 2];
        float a0_4 = z1[o4],     a2_4 = z1[o4 + 2];
        float c0_0 = z2[o0],     c2_0 = z2[o0 + 2];
        float c0_1 = z2[o1],     c2_1 = z2[o1 + 2];
        float c0_2 = z2[o2],     c2_2 = z2[o2 + 2];
        float c0_3 = z2[o3],     c2_3 = z2[o3 + 2];
        float c0_4 = z2[o4],     c2_4 = z2[o4 + 2];

        const int id0 = rho_bin(a0_0, a2_0, c0_0, c2_0);
        const int id1 = rho_bin(a0_1, a2_1, c0_1, c2_1);
        const int id2 = rho_bin(a0_2, a2_2, c0_2, c2_2);
        const int id3 = rho_bin(a0_3, a2_3, c0_3, c2_3);
        const int id4 = rho_bin(a0_4, a2_4, c0_4, c2_4);

        // 5 independent dependent-gathers overlap each other
        float g0 = dg[r0 * GD + id0];
        float g1 = dg[r1 * GD + id1];
        float g2 = dg[r2 * GD + id2];
        float g3 = dg[r3 * GD + id3];
        float g4 = dg[r4 * GD + id4];

        out[r0] = g0;
        out[r1] = g1;
        out[r2] = g2;
        out[r3] = g3;
        out[r4] = g4;
    }

    // ---- tail: <=1 row per thread for B = 4,000,000 with T = 262,144 ----
    for (; i < B; i += T) {
        const int o = i * ZD;
        const int id = rho_bin(z1[o], z1[o + 2], z2[o], z2[o + 2]);
        out[i] = dg[i * GD + id];
    }
}

extern "C" void kernel_launch(void* const* d_in, const int* in_sizes, int n_in,
                              void* d_out, int out_size, void* d_ws, size_t ws_size,
                              hipStream_t stream) {
    const float* z1 = (const float*)d_in[0];
    const float* z2 = (const float*)d_in[1];
    const float* dg = (const float*)d_in[2];
    float* out = (float*)d_out;

    int B = out_size;  // 4,000,000
    const int block = 256;
    int grid = 1024;                       // 4 blocks/CU, T = 262144, B/T ~ 15.26
    int max_grid = (B + block - 1) / block;
    if (grid > max_grid) grid = max_grid;  // small-B safety
    rho_valuation_kernel<<<grid, block, 0, stream>>>(z1, z2, dg, out, B);
}

// Round 3
// 442.642 us; speedup vs baseline: 1.0052x; 1.0052x over previous
//
#include <hip/hip_runtime.h>

// FCNNRhoValuationFunction: rho = sqrt((z2c0-z1c0)^2 + (z1c2-z2c2)^2),
// dist_id = #{k in 1..9 : rho >= k*0.1f}, out[b] = dist_grade[b][dist_id].
//
// Evidence so far (all ~153-158 us/dispatch, 528 MB L2-miss traffic, 3.4 TB/s
// delivered):
//   R1 scalar/short-blocks = 154, R2 LDS-coalesced = 153, R3 deep-ILP = 158.
//   Structure-invariant AND sourcing-invariant (LLC-warm pass-2 dispatches ran
//   at the same time with near-zero HBM fetch). VALUBusy ~2-4%. Line-level
//   footprint (528 MB) is irreducible: per-row byte gaps < 128 B line size.
// Last untested lever: concurrency. All prior runs sat at 35-42% occupancy
// (R1/R2: one-shot block churn; R3: grid=1024 caps at 16/32 waves/CU).
// Little's law: 3.4 TB/s ~= 256 CU x ~105 lines-in-flight / ~1 us loaded
// latency -> if miss-generation rate is the limit, 2x resident waves -> 2x
// in-flight misses.
//
// R4 (re-run; previous attempt died to a container-infra failure, kernel
// never executed): grid = 2048 blocks x 256 threads = 8 blocks/CU =
// 32 waves/CU (100% occupancy cap), __launch_bounds__(256,8) pins VGPR<=64
// so occupancy is not register-limited. 4-row batches (~7.6 rows/thread),
// no LDS, no barriers. If time does not move at ~90% occupancy, the evidence
// triangle is complete (structure/sourcing/occupancy-invariant) =>
// memory-system ceiling, stop.
//
// IEEE ops (__f*_rn) keep us bit-identical to the numpy f32 reference:
// a 1-ulp diff can flip a threshold compare and change out by O(1).

#define ZD 11
#define GD 10

__device__ __forceinline__ int rho_bin(float a0, float a2, float c0, float c2)
{
    float dx  = __fadd_rn(c0, -a0);
    float dy  = __fadd_rn(a2, -c2);
    float s   = __fadd_rn(__fmul_rn(dx, dx), __fmul_rn(dy, dy));
    float rho = __fsqrt_rn(s);
    int id = 0;
    #pragma unroll
    for (int k = 1; k <= 9; ++k)
        id += (rho >= (float)k * 0.1f) ? 1 : 0;
    return id;
}

__global__ __launch_bounds__(256, 8) void rho_valuation_kernel(
    const float* __restrict__ z1,
    const float* __restrict__ z2,
    const float* __restrict__ dg,
    float* __restrict__ out,
    int B)
{
    const int T = gridDim.x * blockDim.x;   // 524288: B/T ~ 7.63 rows/thread
    int i = blockIdx.x * blockDim.x + threadIdx.x;

    // ---- main: 4-row batches, all-int indexing (max index 44M < 2^31) ----
    for (; i + 3 * T < B; i += 4 * T) {
        const int r0 = i, r1 = i + T, r2 = i + 2 * T, r3 = i + 3 * T;
        const int o0 = r0 * ZD, o1 = r1 * ZD, o2 = r2 * ZD, o3 = r3 * ZD;

        // 16 independent scalar loads issued back-to-back
        float a0_0 = z1[o0], a2_0 = z1[o0 + 2];
        float a0_1 = z1[o1], a2_1 = z1[o1 + 2];
        float a0_2 = z1[o2], a2_2 = z1[o2 + 2];
        float a0_3 = z1[o3], a2_3 = z1[o3 + 2];
        float c0_0 = z2[o0], c2_0 = z2[o0 + 2];
        float c0_1 = z2[o1], c2_1 = z2[o1 + 2];
        float c0_2 = z2[o2], c2_2 = z2[o2 + 2];
        float c0_3 = z2[o3], c2_3 = z2[o3 + 2];

        const int id0 = rho_bin(a0_0, a2_0, c0_0, c2_0);
        const int id1 = rho_bin(a0_1, a2_1, c0_1, c2_1);
        const int id2 = rho_bin(a0_2, a2_2, c0_2, c2_2);
        const int id3 = rho_bin(a0_3, a2_3, c0_3, c2_3);

        // 4 independent dependent-gathers overlap each other
        float g0 = dg[r0 * GD + id0];
        float g1 = dg[r1 * GD + id1];
        float g2 = dg[r2 * GD + id2];
        float g3 = dg[r3 * GD + id3];

        out[r0] = g0;
        out[r1] = g1;
        out[r2] = g2;
        out[r3] = g3;
    }

    // ---- tail: <=4 rows per thread ----
    for (; i < B; i += T) {
        const int o = i * ZD;
        const int id = rho_bin(z1[o], z1[o + 2], z2[o], z2[o + 2]);
        out[i] = dg[i * GD + id];
    }
}

extern "C" void kernel_launch(void* const* d_in, const int* in_sizes, int n_in,
                              void* d_out, int out_size, void* d_ws, size_t ws_size,
                              hipStream_t stream) {
    const float* z1 = (const float*)d_in[0];
    const float* z2 = (const float*)d_in[1];
    const float* dg = (const float*)d_in[2];
    float* out = (float*)d_out;

    int B = out_size;  // 4,000,000
    const int block = 256;
    int grid = 2048;                       // 8 blocks/CU -> 32 waves/CU (100% cap)
    int max_grid = (B + block - 1) / block;
    if (grid > max_grid) grid = max_grid;  // small-B safety
    rho_valuation_kernel<<<grid, block, 0, stream>>>(z1, z2, dg, out, B);
}